// Round 1
// baseline (172.989 us; speedup 1.0000x reference)
//
#include <hip/hip_runtime.h>

#define H 512
#define W 512
#define TILE 64
#define TG_ROWS 68      // TILE + 4 halo rows
#define TG_C4 18        // float4 chunks per staged row (72 floats: x0-4 .. x0+67)
#define TG_STRIDE 76    // padded row stride in floats (304 B, 16B-aligned, even bank spread)

// Kernel 1: per-tile partial sums of 25 shifted intersections + i_sum + t_sum.
__global__ __launch_bounds__(256, 2)
void dice_partial(const float* __restrict__ in, const float* __restrict__ tg,
                  float* __restrict__ ws, int nblocks) {
    __shared__ float tgs[TG_ROWS * TG_STRIDE];

    const int bx = blockIdx.x, by = blockIdx.y, b = blockIdx.z;
    const int x0 = bx * TILE, y0 = by * TILE;
    const size_t ibase = (size_t)b * (H * W);
    const int tid = threadIdx.x;

    // ---- stage target halo tile (rows y0-2..y0+65, float cols x0-4..x0+67) ----
    const int x40 = x0 >> 2;   // float4 index of tile start
    for (int idx = tid; idx < TG_ROWS * TG_C4; idx += 256) {
        const int rr = idx / TG_C4;
        const int c4 = idx - rr * TG_C4;
        const int gy  = (y0 - 2 + rr) & (H - 1);
        const int gx4 = (x40 - 1 + c4) & (W / 4 - 1);
        const float4 v = *reinterpret_cast<const float4*>(tg + ibase + (size_t)gy * W + (size_t)gx4 * 4);
        *reinterpret_cast<float4*>(&tgs[rr * TG_STRIDE + c4 * 4]) = v;
    }

    // ---- this thread's 16 input pixels: row r, cols x0+16*s .. +15 ----
    const int r = tid >> 2;        // 0..63 tile row
    const int sseg = tid & 3;      // 0..3 segment
    const float* ip = in + ibase + (size_t)(y0 + r) * W + x0 + sseg * 16;
    float iv[16];
#pragma unroll
    for (int k = 0; k < 4; ++k) {
        const float4 v = *reinterpret_cast<const float4*>(ip + 4 * k);
        iv[4*k+0] = v.x; iv[4*k+1] = v.y; iv[4*k+2] = v.z; iv[4*k+3] = v.w;
    }
    float isum = 0.f;
#pragma unroll
    for (int k = 0; k < 16; ++k) isum += iv[k];

    __syncthreads();

    // ---- 25 shifted dot products, all static-indexed registers ----
    float acc[25];
#pragma unroll
    for (int k = 0; k < 25; ++k) acc[k] = 0.f;
    float tsum = 0.f;

#pragma unroll
    for (int t = 0; t < 5; ++t) {
        float wrow[24];
        const float* base = &tgs[(r + t) * TG_STRIDE + sseg * 16];
#pragma unroll
        for (int k = 0; k < 6; ++k) {
            const float4 v = *reinterpret_cast<const float4*>(base + 4 * k);
            wrow[4*k+0] = v.x; wrow[4*k+1] = v.y; wrow[4*k+2] = v.z; wrow[4*k+3] = v.w;
        }
        if (t == 2) {   // center row: each target element counted exactly once globally
#pragma unroll
            for (int px = 0; px < 16; ++px) tsum += wrow[px + 4];
        }
#pragma unroll
        for (int ss = 0; ss < 5; ++ss) {
#pragma unroll
            for (int px = 0; px < 16; ++px)
                acc[t * 5 + ss] += iv[px] * wrow[px + 6 - ss];
        }
    }

    // ---- block reduction of 27 values ----
    float vals[27];
#pragma unroll
    for (int k = 0; k < 25; ++k) vals[k] = acc[k];
    vals[25] = isum; vals[26] = tsum;

#pragma unroll
    for (int off = 32; off; off >>= 1) {
#pragma unroll
        for (int k = 0; k < 27; ++k) vals[k] += __shfl_down(vals[k], off, 64);
    }

    __syncthreads();   // done reading tgs; safe to reuse
    const int wave = tid >> 6, lane = tid & 63;
    if (lane == 0) {
#pragma unroll
        for (int k = 0; k < 27; ++k) tgs[wave * 27 + k] = vals[k];
    }
    __syncthreads();
    if (tid < 27) {
        const float s = tgs[tid] + tgs[27 + tid] + tgs[54 + tid] + tgs[81 + tid];
        const int bid = (b * (int)gridDim.y + by) * (int)gridDim.x + bx;
        ws[tid * nblocks + bid] = s;   // [k][block] layout for coalesced pass 2
    }
}

// Kernel 2: reduce per-block partials, compute final loss scalar.
__global__ __launch_bounds__(256)
void dice_final(const float* __restrict__ ws, float* __restrict__ out, int nblocks) {
    __shared__ float red[4];
    __shared__ float tot[27];
    const int tid = threadIdx.x;

    for (int k = 0; k < 27; ++k) {
        float s = 0.f;
        for (int i = tid; i < nblocks; i += 256) s += ws[k * nblocks + i];
#pragma unroll
        for (int off = 32; off; off >>= 1) s += __shfl_down(s, off, 64);
        if ((tid & 63) == 0) red[tid >> 6] = s;
        __syncthreads();
        if (tid == 0) tot[k] = red[0] + red[1] + red[2] + red[3];
        __syncthreads();
    }

    if (tid == 0) {
        float m = tot[0];
#pragma unroll
        for (int k = 1; k < 25; ++k) m = fmaxf(m, tot[k]);
        const float denom = tot[25] + tot[26] + 1.0f;   // i_sum + t_sum + SMOOTH
        out[0] = 1.0f - (2.0f * m + 1.0f) / denom;      // min loss == max intersection
    }
}

extern "C" void kernel_launch(void* const* d_in, const int* in_sizes, int n_in,
                              void* d_out, int out_size, void* d_ws, size_t ws_size,
                              hipStream_t stream) {
    const float* inputs  = (const float*)d_in[0];
    const float* targets = (const float*)d_in[1];
    float* out = (float*)d_out;
    float* ws  = (float*)d_ws;

    const int B = in_sizes[0] / (H * W);        // 64
    const int tx = W / TILE, ty = H / TILE;     // 8 x 8
    const int nblocks = B * tx * ty;            // 4096

    dim3 grid(tx, ty, B);
    dice_partial<<<grid, 256, 0, stream>>>(inputs, targets, ws, nblocks);
    dice_final<<<1, 256, 0, stream>>>(ws, out, nblocks);
}

// Round 2
// 68.827 us; speedup vs baseline: 2.5134x; 2.5134x over previous
//
#include <hip/hip_runtime.h>

#define H 512
#define W 512
#define TILE 64
#define TG_ROWS 68      // TILE + 4 halo rows
#define TG_C4 18        // float4 chunks per staged row (72 floats: x0-4 .. x0+67)
#define TG_STRIDE 76    // padded row stride in floats (304 B, 16B-aligned, even bank spread)

// Kernel 1: per-tile partial sums of 25 shifted intersections + i_sum + t_sum.
__global__ __launch_bounds__(256, 3)
void dice_partial(const float* __restrict__ in, const float* __restrict__ tg,
                  float* __restrict__ ws, int nblocks) {
    __shared__ float tgs[TG_ROWS * TG_STRIDE];

    const int bx = blockIdx.x, by = blockIdx.y, b = blockIdx.z;
    const int x0 = bx * TILE, y0 = by * TILE;
    const size_t ibase = (size_t)b * (H * W);
    const int tid = threadIdx.x;

    // ---- stage target halo tile (rows y0-2..y0+65, float cols x0-4..x0+67) ----
    const int x40 = x0 >> 2;   // float4 index of tile start
    for (int idx = tid; idx < TG_ROWS * TG_C4; idx += 256) {
        const int rr = idx / TG_C4;
        const int c4 = idx - rr * TG_C4;
        const int gy  = (y0 - 2 + rr) & (H - 1);
        const int gx4 = (x40 - 1 + c4) & (W / 4 - 1);
        const float4 v = *reinterpret_cast<const float4*>(tg + ibase + (size_t)gy * W + (size_t)gx4 * 4);
        *reinterpret_cast<float4*>(&tgs[rr * TG_STRIDE + c4 * 4]) = v;
    }

    // ---- this thread's 16 input pixels: row r, cols x0+16*s .. +15 ----
    const int r = tid >> 2;        // 0..63 tile row
    const int sseg = tid & 3;      // 0..3 segment
    const float* ip = in + ibase + (size_t)(y0 + r) * W + x0 + sseg * 16;
    float iv[16];
#pragma unroll
    for (int k = 0; k < 4; ++k) {
        const float4 v = *reinterpret_cast<const float4*>(ip + 4 * k);
        iv[4*k+0] = v.x; iv[4*k+1] = v.y; iv[4*k+2] = v.z; iv[4*k+3] = v.w;
    }
    float isum = 0.f;
#pragma unroll
    for (int k = 0; k < 16; ++k) isum += iv[k];

    __syncthreads();

    // ---- 25 shifted dot products, all static-indexed registers ----
    float acc[25];
#pragma unroll
    for (int k = 0; k < 25; ++k) acc[k] = 0.f;
    float tsum = 0.f;

#pragma unroll
    for (int t = 0; t < 5; ++t) {
        float wrow[24];
        const float* base = &tgs[(r + t) * TG_STRIDE + sseg * 16];
#pragma unroll
        for (int k = 0; k < 6; ++k) {
            const float4 v = *reinterpret_cast<const float4*>(base + 4 * k);
            wrow[4*k+0] = v.x; wrow[4*k+1] = v.y; wrow[4*k+2] = v.z; wrow[4*k+3] = v.w;
        }
        if (t == 2) {   // center row: each target element counted exactly once globally
#pragma unroll
            for (int px = 0; px < 16; ++px) tsum += wrow[px + 4];
        }
#pragma unroll
        for (int ss = 0; ss < 5; ++ss) {
#pragma unroll
            for (int px = 0; px < 16; ++px)
                acc[t * 5 + ss] += iv[px] * wrow[px + 6 - ss];
        }
    }

    // ---- block reduction of 27 values ----
    float vals[27];
#pragma unroll
    for (int k = 0; k < 25; ++k) vals[k] = acc[k];
    vals[25] = isum; vals[26] = tsum;

#pragma unroll
    for (int off = 32; off; off >>= 1) {
#pragma unroll
        for (int k = 0; k < 27; ++k) vals[k] += __shfl_down(vals[k], off, 64);
    }

    __syncthreads();   // done reading tgs; safe to reuse
    const int wave = tid >> 6, lane = tid & 63;
    if (lane == 0) {
#pragma unroll
        for (int k = 0; k < 27; ++k) tgs[wave * 27 + k] = vals[k];
    }
    __syncthreads();
    if (tid < 27) {
        const float s = tgs[tid] + tgs[27 + tid] + tgs[54 + tid] + tgs[81 + tid];
        const int bid = (b * (int)gridDim.y + by) * (int)gridDim.x + bx;
        ws[tid * nblocks + bid] = s;   // [k][block] layout for coalesced pass 2
    }
}

// Kernel 2: 27 blocks, block k tree-reduces the 4096 partials for quantity k.
__global__ __launch_bounds__(256)
void dice_reduce(const float* __restrict__ ws, float* __restrict__ tot, int nblocks) {
    __shared__ float red[4];
    const int k = blockIdx.x;
    const int tid = threadIdx.x;
    const float* p = ws + (size_t)k * nblocks;

    float s = 0.f;
    for (int i = tid; i < nblocks; i += 256) s += p[i];   // 16 coalesced loads/thread
#pragma unroll
    for (int off = 32; off; off >>= 1) s += __shfl_down(s, off, 64);
    if ((tid & 63) == 0) red[tid >> 6] = s;
    __syncthreads();
    if (tid == 0) tot[k] = red[0] + red[1] + red[2] + red[3];
}

// Kernel 3: one wave — 25-way max + final loss scalar.
__global__ void dice_out(const float* __restrict__ tot, float* __restrict__ out) {
    const int tid = threadIdx.x;   // blockDim = 64, all lanes active
    float v = (tid < 25) ? tot[tid] : -1e30f;
#pragma unroll
    for (int off = 32; off; off >>= 1) v = fmaxf(v, __shfl_down(v, off, 64));
    if (tid == 0) {
        const float denom = tot[25] + tot[26] + 1.0f;   // i_sum + t_sum + SMOOTH
        out[0] = 1.0f - (2.0f * v + 1.0f) / denom;      // min loss == max intersection
    }
}

extern "C" void kernel_launch(void* const* d_in, const int* in_sizes, int n_in,
                              void* d_out, int out_size, void* d_ws, size_t ws_size,
                              hipStream_t stream) {
    const float* inputs  = (const float*)d_in[0];
    const float* targets = (const float*)d_in[1];
    float* out = (float*)d_out;
    float* ws  = (float*)d_ws;

    const int B = in_sizes[0] / (H * W);        // 64
    const int tx = W / TILE, ty = H / TILE;     // 8 x 8
    const int nblocks = B * tx * ty;            // 4096

    float* tot = ws + (size_t)27 * nblocks;     // 27 scalar totals after the partial table

    dim3 grid(tx, ty, B);
    dice_partial<<<grid, 256, 0, stream>>>(inputs, targets, ws, nblocks);
    dice_reduce<<<27, 256, 0, stream>>>(ws, tot, nblocks);
    dice_out<<<1, 64, 0, stream>>>(tot, out);
}

// Round 3
// 65.924 us; speedup vs baseline: 2.6241x; 1.0440x over previous
//
#include <hip/hip_runtime.h>

#define H 512
#define W 512
#define TILE 64
#define TG_ROWS 68      // TILE + 4 halo rows
#define TG_C4 18        // float4 chunks per staged row (72 floats: x0-4 .. x0+67)
#define TG_STRIDE 76    // padded row stride in floats (304 B, 16B-aligned, even bank spread)

// Kernel 1: per-tile partial sums of 25 shifted intersections + i_sum + t_sum.
// Per-t wave reduction keeps live accumulators at 5 (not 25) -> VGPR <= 64 ->
// 8-waves/SIMD occupancy bucket; LDS (21 KB) then caps residency at 7 blocks/CU.
__global__ __launch_bounds__(256, 8)
void dice_partial(const float* __restrict__ in, const float* __restrict__ tg,
                  float* __restrict__ ws, int nblocks) {
    __shared__ float tgs[TG_ROWS * TG_STRIDE];
    __shared__ float warr[4][32];   // [wave][quantity 0..26], padded row

    const int bx = blockIdx.x, by = blockIdx.y, b = blockIdx.z;
    const int x0 = bx * TILE, y0 = by * TILE;
    const size_t ibase = (size_t)b * (H * W);
    const int tid = threadIdx.x;
    const int wave = tid >> 6, lane = tid & 63;

    // ---- stage target halo tile (rows y0-2..y0+65, float cols x0-4..x0+67) ----
    const int x40 = x0 >> 2;   // float4 index of tile start
    for (int idx = tid; idx < TG_ROWS * TG_C4; idx += 256) {
        const int rr = idx / TG_C4;
        const int c4 = idx - rr * TG_C4;
        const int gy  = (y0 - 2 + rr) & (H - 1);
        const int gx4 = (x40 - 1 + c4) & (W / 4 - 1);
        const float4 v = *reinterpret_cast<const float4*>(tg + ibase + (size_t)gy * W + (size_t)gx4 * 4);
        *reinterpret_cast<float4*>(&tgs[rr * TG_STRIDE + c4 * 4]) = v;
    }

    // ---- this thread's 16 input pixels: row r, cols x0+16*s .. +15 ----
    const int r = tid >> 2;        // 0..63 tile row
    const int sseg = tid & 3;      // 0..3 segment
    const float* ip = in + ibase + (size_t)(y0 + r) * W + x0 + sseg * 16;
    float iv[16];
#pragma unroll
    for (int k = 0; k < 4; ++k) {
        const float4 v = *reinterpret_cast<const float4*>(ip + 4 * k);
        iv[4*k+0] = v.x; iv[4*k+1] = v.y; iv[4*k+2] = v.z; iv[4*k+3] = v.w;
    }
    {
        float isum = 0.f;
#pragma unroll
        for (int k = 0; k < 16; ++k) isum += iv[k];
#pragma unroll
        for (int off = 32; off; off >>= 1) isum += __shfl_down(isum, off, 64);
        if (lane == 0) warr[wave][25] = isum;
    }

    __syncthreads();   // staging complete

    // ---- 25 shifted dot products; reduce 5 accumulators per target row t ----
#pragma unroll
    for (int t = 0; t < 5; ++t) {
        float wrow[24];
        const float* base = &tgs[(r + t) * TG_STRIDE + sseg * 16];
#pragma unroll
        for (int k = 0; k < 6; ++k) {
            const float4 v = *reinterpret_cast<const float4*>(base + 4 * k);
            wrow[4*k+0] = v.x; wrow[4*k+1] = v.y; wrow[4*k+2] = v.z; wrow[4*k+3] = v.w;
        }

        float acc[5];
#pragma unroll
        for (int ss = 0; ss < 5; ++ss) acc[ss] = 0.f;
#pragma unroll
        for (int ss = 0; ss < 5; ++ss) {
#pragma unroll
            for (int px = 0; px < 16; ++px)
                acc[ss] += iv[px] * wrow[px + 6 - ss];
        }

        if (t == 2) {   // center row: each target element counted exactly once globally
            float tsum = 0.f;
#pragma unroll
            for (int px = 0; px < 16; ++px) tsum += wrow[px + 4];
#pragma unroll
            for (int off = 32; off; off >>= 1) tsum += __shfl_down(tsum, off, 64);
            if (lane == 0) warr[wave][26] = tsum;
        }

#pragma unroll
        for (int ss = 0; ss < 5; ++ss) {
            float v = acc[ss];
#pragma unroll
            for (int off = 32; off; off >>= 1) v += __shfl_down(v, off, 64);
            if (lane == 0) warr[wave][t * 5 + ss] = v;
        }
    }

    __syncthreads();
    if (tid < 27) {
        const float s = warr[0][tid] + warr[1][tid] + warr[2][tid] + warr[3][tid];
        const int bid = (b * (int)gridDim.y + by) * (int)gridDim.x + bx;
        ws[tid * nblocks + bid] = s;   // [k][block] layout for coalesced pass 2
    }
}

// Kernel 2: 27 blocks, block k tree-reduces the 4096 partials for quantity k.
__global__ __launch_bounds__(256)
void dice_reduce(const float* __restrict__ ws, float* __restrict__ tot, int nblocks) {
    __shared__ float red[4];
    const int k = blockIdx.x;
    const int tid = threadIdx.x;
    const float* p = ws + (size_t)k * nblocks;

    float s = 0.f;
    for (int i = tid; i < nblocks; i += 256) s += p[i];   // 16 coalesced loads/thread
#pragma unroll
    for (int off = 32; off; off >>= 1) s += __shfl_down(s, off, 64);
    if ((tid & 63) == 0) red[tid >> 6] = s;
    __syncthreads();
    if (tid == 0) tot[k] = red[0] + red[1] + red[2] + red[3];
}

// Kernel 3: one wave — 25-way max + final loss scalar.
__global__ void dice_out(const float* __restrict__ tot, float* __restrict__ out) {
    const int tid = threadIdx.x;   // blockDim = 64, all lanes active
    float v = (tid < 25) ? tot[tid] : -1e30f;
#pragma unroll
    for (int off = 32; off; off >>= 1) v = fmaxf(v, __shfl_down(v, off, 64));
    if (tid == 0) {
        const float denom = tot[25] + tot[26] + 1.0f;   // i_sum + t_sum + SMOOTH
        out[0] = 1.0f - (2.0f * v + 1.0f) / denom;      // min loss == max intersection
    }
}

extern "C" void kernel_launch(void* const* d_in, const int* in_sizes, int n_in,
                              void* d_out, int out_size, void* d_ws, size_t ws_size,
                              hipStream_t stream) {
    const float* inputs  = (const float*)d_in[0];
    const float* targets = (const float*)d_in[1];
    float* out = (float*)d_out;
    float* ws  = (float*)d_ws;

    const int B = in_sizes[0] / (H * W);        // 64
    const int tx = W / TILE, ty = H / TILE;     // 8 x 8
    const int nblocks = B * tx * ty;            // 4096

    float* tot = ws + (size_t)27 * nblocks;     // 27 scalar totals after the partial table

    dim3 grid(tx, ty, B);
    dice_partial<<<grid, 256, 0, stream>>>(inputs, targets, ws, nblocks);
    dice_reduce<<<27, 256, 0, stream>>>(ws, tot, nblocks);
    dice_out<<<1, 64, 0, stream>>>(tot, out);
}

// Round 4
// 47.118 us; speedup vs baseline: 3.6714x; 1.3991x over previous
//
#include <hip/hip_runtime.h>

#define H 512
#define W 512
#define TILE 64
#define TG_ROWS 68      // TILE + 4 halo rows
#define TG_C4 18        // float4 chunks per staged row (72 floats: x0-4 .. x0+67)
#define TG_STRIDE 76    // padded row stride in floats (304 B, 16B-aligned, even bank spread)

// Full-wave (64-lane) sum using DPP only — pure VALU, no DS-pipe traffic.
// After the 6 steps the total is in lane 63. (gfx9-lineage DPP: CDNA keeps
// row_shr and row_bcast:15/31.)
__device__ __forceinline__ float wave_sum_dpp(float x) {
#define DPP_STEP(ctrl)                                                          \
    x += __int_as_float(__builtin_amdgcn_update_dpp(                            \
        0, __float_as_int(x), (ctrl), 0xF, 0xF, true))
    DPP_STEP(0x111);   // row_shr:1
    DPP_STEP(0x112);   // row_shr:2
    DPP_STEP(0x114);   // row_shr:4
    DPP_STEP(0x118);   // row_shr:8   -> lane15 of each row16 holds row sum
    DPP_STEP(0x142);   // row_bcast:15
    DPP_STEP(0x143);   // row_bcast:31 -> lane63 holds full wave sum
#undef DPP_STEP
    return x;
}

// Kernel 1: per-tile partial sums of 25 shifted intersections + i_sum + t_sum.
// All cross-lane reductions are DPP (VALU); the DS pipe only carries the
// staging writes and the wrow reads.
__global__ __launch_bounds__(256, 8)
void dice_partial(const float* __restrict__ in, const float* __restrict__ tg,
                  float* __restrict__ ws, int nblocks) {
    __shared__ float tgs[TG_ROWS * TG_STRIDE];
    __shared__ float warr[4][32];   // [wave][quantity 0..26]

    const int bx = blockIdx.x, by = blockIdx.y, b = blockIdx.z;
    const int x0 = bx * TILE, y0 = by * TILE;
    const size_t ibase = (size_t)b * (H * W);
    const int tid = threadIdx.x;
    const int wave = tid >> 6, lane = tid & 63;

    // ---- stage target halo tile (rows y0-2..y0+65, float cols x0-4..x0+67) ----
    const int x40 = x0 >> 2;   // float4 index of tile start
    for (int idx = tid; idx < TG_ROWS * TG_C4; idx += 256) {
        const int rr = idx / TG_C4;
        const int c4 = idx - rr * TG_C4;
        const int gy  = (y0 - 2 + rr) & (H - 1);
        const int gx4 = (x40 - 1 + c4) & (W / 4 - 1);
        const float4 v = *reinterpret_cast<const float4*>(tg + ibase + (size_t)gy * W + (size_t)gx4 * 4);
        *reinterpret_cast<float4*>(&tgs[rr * TG_STRIDE + c4 * 4]) = v;
    }

    // ---- this thread's 16 input pixels: row r, cols x0+16*s .. +15 ----
    const int r = tid >> 2;        // 0..63 tile row
    const int sseg = tid & 3;      // 0..3 segment
    const float* ip = in + ibase + (size_t)(y0 + r) * W + x0 + sseg * 16;
    float iv[16];
#pragma unroll
    for (int k = 0; k < 4; ++k) {
        const float4 v = *reinterpret_cast<const float4*>(ip + 4 * k);
        iv[4*k+0] = v.x; iv[4*k+1] = v.y; iv[4*k+2] = v.z; iv[4*k+3] = v.w;
    }
    {
        float isum = 0.f;
#pragma unroll
        for (int k = 0; k < 16; ++k) isum += iv[k];
        isum = wave_sum_dpp(isum);
        if (lane == 63) warr[wave][25] = isum;
    }

    __syncthreads();   // staging complete

    // ---- 25 shifted dot products; DPP-reduce 5 accumulators per target row t ----
#pragma unroll
    for (int t = 0; t < 5; ++t) {
        float wrow[24];
        const float* base = &tgs[(r + t) * TG_STRIDE + sseg * 16];
#pragma unroll
        for (int k = 0; k < 6; ++k) {
            const float4 v = *reinterpret_cast<const float4*>(base + 4 * k);
            wrow[4*k+0] = v.x; wrow[4*k+1] = v.y; wrow[4*k+2] = v.z; wrow[4*k+3] = v.w;
        }

        float acc[5];
#pragma unroll
        for (int ss = 0; ss < 5; ++ss) acc[ss] = 0.f;
#pragma unroll
        for (int ss = 0; ss < 5; ++ss) {
#pragma unroll
            for (int px = 0; px < 16; ++px)
                acc[ss] += iv[px] * wrow[px + 6 - ss];
        }

        if (t == 2) {   // center row: each target element counted exactly once globally
            float tsum = 0.f;
#pragma unroll
            for (int px = 0; px < 16; ++px) tsum += wrow[px + 4];
            tsum = wave_sum_dpp(tsum);
            if (lane == 63) warr[wave][26] = tsum;
        }

#pragma unroll
        for (int ss = 0; ss < 5; ++ss) {
            const float v = wave_sum_dpp(acc[ss]);
            if (lane == 63) warr[wave][t * 5 + ss] = v;
        }
    }

    __syncthreads();
    if (tid < 27) {
        const float s = warr[0][tid] + warr[1][tid] + warr[2][tid] + warr[3][tid];
        const int bid = (b * (int)gridDim.y + by) * (int)gridDim.x + bx;
        ws[tid * nblocks + bid] = s;   // [k][block] layout for coalesced pass 2
    }
}

// Kernel 2: 27 blocks, block k tree-reduces the 4096 partials for quantity k.
__global__ __launch_bounds__(256)
void dice_reduce(const float* __restrict__ ws, float* __restrict__ tot, int nblocks) {
    __shared__ float red[4];
    const int k = blockIdx.x;
    const int tid = threadIdx.x;
    const float* p = ws + (size_t)k * nblocks;

    float s = 0.f;
    for (int i = tid; i < nblocks; i += 256) s += p[i];   // 16 coalesced loads/thread
    s = wave_sum_dpp(s);
    if ((tid & 63) == 63) red[tid >> 6] = s;
    __syncthreads();
    if (tid == 0) tot[k] = red[0] + red[1] + red[2] + red[3];
}

// Kernel 3: one wave — 25-way max + final loss scalar.
__global__ void dice_out(const float* __restrict__ tot, float* __restrict__ out) {
    const int tid = threadIdx.x;   // blockDim = 64, all lanes active
    float v = (tid < 25) ? tot[tid] : -1e30f;
#pragma unroll
    for (int off = 32; off; off >>= 1) v = fmaxf(v, __shfl_down(v, off, 64));
    if (tid == 0) {
        const float denom = tot[25] + tot[26] + 1.0f;   // i_sum + t_sum + SMOOTH
        out[0] = 1.0f - (2.0f * v + 1.0f) / denom;      // min loss == max intersection
    }
}

extern "C" void kernel_launch(void* const* d_in, const int* in_sizes, int n_in,
                              void* d_out, int out_size, void* d_ws, size_t ws_size,
                              hipStream_t stream) {
    const float* inputs  = (const float*)d_in[0];
    const float* targets = (const float*)d_in[1];
    float* out = (float*)d_out;
    float* ws  = (float*)d_ws;

    const int B = in_sizes[0] / (H * W);        // 64
    const int tx = W / TILE, ty = H / TILE;     // 8 x 8
    const int nblocks = B * tx * ty;            // 4096

    float* tot = ws + (size_t)27 * nblocks;     // 27 scalar totals after the partial table

    dim3 grid(tx, ty, B);
    dice_partial<<<grid, 256, 0, stream>>>(inputs, targets, ws, nblocks);
    dice_reduce<<<27, 256, 0, stream>>>(ws, tot, nblocks);
    dice_out<<<1, 64, 0, stream>>>(tot, out);
}

// Round 5
// 41.202 us; speedup vs baseline: 4.1986x; 1.1436x over previous
//
#include <hip/hip_runtime.h>

#define H 512
#define W 512

// Full-wave (64-lane) sum using DPP only — pure VALU, no DS-pipe traffic.
// After the 6 steps the total is in lane 63. (HW-verified in R4.)
__device__ __forceinline__ float wave_sum_dpp(float x) {
#define DPP_STEP(ctrl)                                                          \
    x += __int_as_float(__builtin_amdgcn_update_dpp(                            \
        0, __float_as_int(x), (ctrl), 0xF, 0xF, true))
    DPP_STEP(0x111);   // row_shr:1
    DPP_STEP(0x112);   // row_shr:2
    DPP_STEP(0x114);   // row_shr:4
    DPP_STEP(0x118);   // row_shr:8   -> lane15 of each row16 holds row sum
    DPP_STEP(0x142);   // row_bcast:15
    DPP_STEP(0x143);   // row_bcast:31 -> lane63 holds full wave sum
#undef DPP_STEP
    return x;
}

__device__ __forceinline__ float4 ld4(const float* p) {
    return *reinterpret_cast<const float4*>(p);
}

// Kernel 1: register-resident row-quad kernel. One wave owns 4 full image rows
// (64 lanes x 8 px = 512 = W). No LDS tile, no __syncthreads in the hot path,
// no bank conflicts. Column halo (+-2, wrapping mod 512) comes from lane+-1
// via __shfl; row wrap is plain index math. 800 static-register FMAs/lane.
__global__ __launch_bounds__(256, 4)
void dice_partial(const float* __restrict__ in, const float* __restrict__ tg,
                  float* __restrict__ ws, int nblocks) {
    __shared__ float warr[4][32];   // [wave][quantity 0..26]

    const int tid  = threadIdx.x;
    const int wave = tid >> 6, lane = tid & 63;

    // Bijective XCD chunking (nblocks % 8 == 0): consecutive quads (which share
    // 2 target halo rows) stay on one XCD's L2.
    const int bid = blockIdx.x;
    const int wrk = (bid & 7) * (nblocks >> 3) + (bid >> 3);

    const int q  = wrk * 4 + wave;        // global row-quad id, 0..8191
    const int b  = q >> 7;                // batch (128 quads per image)
    const int y0 = (q & 127) << 2;        // first of 4 owned rows
    const size_t ibase = (size_t)b * (H * W);

    const int laneL = (lane + 63) & 63;   // left neighbor (wraps: col -1 -> 511)
    const int laneR = (lane + 1) & 63;

    // ---- 4 input rows into registers ----
    const float* ibp = in + ibase + (size_t)y0 * W + lane * 8;
    float iv[4][8];
    float isum = 0.f;
#pragma unroll
    for (int yi = 0; yi < 4; ++yi) {
        const float4 a = ld4(ibp + (size_t)yi * W);
        const float4 c = ld4(ibp + (size_t)yi * W + 4);
        iv[yi][0] = a.x; iv[yi][1] = a.y; iv[yi][2] = a.z; iv[yi][3] = a.w;
        iv[yi][4] = c.x; iv[yi][5] = c.y; iv[yi][6] = c.z; iv[yi][7] = c.w;
#pragma unroll
        for (int j = 0; j < 8; ++j) isum += iv[yi][j];
    }

    float acc[25];
#pragma unroll
    for (int k = 0; k < 25; ++k) acc[k] = 0.f;
    float tsum = 0.f;

    // ---- 8 target rows (y0-2 .. y0+5, wrapped); each feeds up to 4 in-rows ----
#pragma unroll
    for (int t = 0; t < 8; ++t) {
        const int yt = (y0 - 2 + t) & (H - 1);
        const float* tp = tg + ibase + (size_t)yt * W + lane * 8;

        float tw[12];   // columns 8*lane-2 .. 8*lane+9 (tw[c] = col 8*lane + c - 2)
        const float4 a = ld4(tp);
        const float4 c = ld4(tp + 4);
        tw[2] = a.x; tw[3] = a.y; tw[4] = a.z; tw[5] = a.w;
        tw[6] = c.x; tw[7] = c.y; tw[8] = c.z; tw[9] = c.w;
        tw[0]  = __shfl(tw[8], laneL, 64);   // col 8l-2
        tw[1]  = __shfl(tw[9], laneL, 64);   // col 8l-1
        tw[10] = __shfl(tw[2], laneR, 64);   // col 8l+8
        tw[11] = __shfl(tw[3], laneR, 64);   // col 8l+9

        if (t >= 2 && t <= 5) {              // rows y0..y0+3: count each tg elem once
#pragma unroll
            for (int j = 0; j < 8; ++j) tsum += tw[j + 2];
        }

#pragma unroll
        for (int yi = 0; yi < 4; ++yi) {
            const int sy = yi + 2 - t;       // roll shift: in row yi pairs tg row yt
            if (sy < -2 || sy > 2) continue; // compile-time prune (20 live pairs)
#pragma unroll
            for (int sx = -2; sx <= 2; ++sx) {
#pragma unroll
                for (int j = 0; j < 8; ++j)
                    acc[(sy + 2) * 5 + (sx + 2)] += iv[yi][j] * tw[j + 2 - sx];
            }
        }
    }

    // ---- per-wave DPP reduction of 27 quantities, then per-block combine ----
#pragma unroll
    for (int k = 0; k < 25; ++k) {
        const float v = wave_sum_dpp(acc[k]);
        if (lane == 63) warr[wave][k] = v;
    }
    {
        const float v = wave_sum_dpp(isum);
        if (lane == 63) warr[wave][25] = v;
        const float u = wave_sum_dpp(tsum);
        if (lane == 63) warr[wave][26] = u;
    }

    __syncthreads();
    if (tid < 27) {
        const float s = warr[0][tid] + warr[1][tid] + warr[2][tid] + warr[3][tid];
        ws[tid * nblocks + bid] = s;   // [k][block] layout for coalesced pass 2
    }
}

// Kernel 2: 27 blocks, block k tree-reduces the per-block partials for quantity k.
__global__ __launch_bounds__(256)
void dice_reduce(const float* __restrict__ ws, float* __restrict__ tot, int nblocks) {
    __shared__ float red[4];
    const int k = blockIdx.x;
    const int tid = threadIdx.x;
    const float* p = ws + (size_t)k * nblocks;

    float s = 0.f;
    for (int i = tid; i < nblocks; i += 256) s += p[i];
    s = wave_sum_dpp(s);
    if ((tid & 63) == 63) red[tid >> 6] = s;
    __syncthreads();
    if (tid == 0) tot[k] = red[0] + red[1] + red[2] + red[3];
}

// Kernel 3: one wave — 25-way max + final loss scalar.
__global__ void dice_out(const float* __restrict__ tot, float* __restrict__ out) {
    const int tid = threadIdx.x;   // blockDim = 64
    float v = (tid < 25) ? tot[tid] : -1e30f;
#pragma unroll
    for (int off = 32; off; off >>= 1) v = fmaxf(v, __shfl_down(v, off, 64));
    if (tid == 0) {
        const float denom = tot[25] + tot[26] + 1.0f;   // i_sum + t_sum + SMOOTH
        out[0] = 1.0f - (2.0f * v + 1.0f) / denom;      // min loss == max intersection
    }
}

extern "C" void kernel_launch(void* const* d_in, const int* in_sizes, int n_in,
                              void* d_out, int out_size, void* d_ws, size_t ws_size,
                              hipStream_t stream) {
    const float* inputs  = (const float*)d_in[0];
    const float* targets = (const float*)d_in[1];
    float* out = (float*)d_out;
    float* ws  = (float*)d_ws;

    const int B = in_sizes[0] / (H * W);    // 64
    const int nblocks = B * (H / 4) / 4;    // 2048 blocks x 4 waves x 4 rows = all rows

    float* tot = ws + (size_t)27 * nblocks; // 27 scalar totals after the partial table

    dice_partial<<<nblocks, 256, 0, stream>>>(inputs, targets, ws, nblocks);
    dice_reduce<<<27, 256, 0, stream>>>(ws, tot, nblocks);
    dice_out<<<1, 64, 0, stream>>>(tot, out);
}

// Round 6
// 40.224 us; speedup vs baseline: 4.3007x; 1.0243x over previous
//
#include <hip/hip_runtime.h>

#define H 512
#define W 512

// Full-wave (64-lane) sum using DPP only — pure VALU, no DS-pipe traffic.
// After the 6 steps the total is in lane 63. (HW-verified R4/R5.)
__device__ __forceinline__ float wave_sum_dpp(float x) {
#define DPP_STEP(ctrl)                                                          \
    x += __int_as_float(__builtin_amdgcn_update_dpp(                            \
        0, __float_as_int(x), (ctrl), 0xF, 0xF, true))
    DPP_STEP(0x111);   // row_shr:1
    DPP_STEP(0x112);   // row_shr:2
    DPP_STEP(0x114);   // row_shr:4
    DPP_STEP(0x118);   // row_shr:8   -> lane15 of each row16 holds row sum
    DPP_STEP(0x142);   // row_bcast:15
    DPP_STEP(0x143);   // row_bcast:31 -> lane63 holds full wave sum
#undef DPP_STEP
    return x;
}

__device__ __forceinline__ float4 ld4(const float* p) {
    return *reinterpret_cast<const float4*>(p);
}

// Kernel 1: register-resident row-quad kernel, zero cross-lane ops in the hot
// path. One wave owns 4 full image rows (64 lanes x 8 px = 512 = W). The +-2
// column halo is DIRECT-LOADED per lane from the two adjacent aligned float4
// chunks (L1-hit: they are neighbor lanes' main chunks) — no __shfl, so no
// DS-pipe latency chained behind each global load. Target rows flow through a
// 3-slot register pipeline with depth-2 prefetch (all indices compile-time).
__global__ __launch_bounds__(256, 4)
void dice_partial(const float* __restrict__ in, const float* __restrict__ tg,
                  float* __restrict__ ws, int nblocks) {
    __shared__ float warr[4][32];   // [wave][quantity 0..26]

    const int tid  = threadIdx.x;
    const int wave = tid >> 6, lane = tid & 63;

    // Bijective XCD chunking (nblocks % 8 == 0): consecutive quads (which share
    // target halo rows) stay on one XCD's L2.
    const int bid = blockIdx.x;
    const int wrk = (bid & 7) * (nblocks >> 3) + (bid >> 3);

    const int q  = wrk * 4 + wave;        // global row-quad id
    const int b  = q >> 7;                // batch (128 quads per image)
    const int y0 = (q & 127) << 2;        // first of 4 owned rows (<= 508)
    const float* __restrict__ ib = in + (size_t)b * (H * W);
    const float* __restrict__ tb = tg + (size_t)b * (H * W);

    const int c0 = lane * 8;              // my 8 columns: c0..c0+7
    const int cL = (c0 - 4) & (W - 1);    // left halo chunk (wraps)
    const int cR = (c0 + 8) & (W - 1);    // right halo chunk (wraps)

    // ---- issue the 8 input-row loads ----
    float4 ia[4], ic[4];
#pragma unroll
    for (int yi = 0; yi < 4; ++yi) {
        const float* rp = ib + (size_t)(y0 + yi) * W;   // y0+3 <= 511, no wrap
        ia[yi] = ld4(rp + c0);
        ic[yi] = ld4(rp + c0 + 4);
    }

    // ---- 3-slot target-row pipeline: row t -> 4 aligned float4 loads ----
    float4 pa[3], pc[3], pl[3], pr[3];
#define TROW(t) (tb + (size_t)((y0 - 2 + (t)) & (H - 1)) * W)
#define ISSUE(slot, t) {                                        \
        const float* tp = TROW(t);                              \
        pa[slot] = ld4(tp + c0);                                \
        pc[slot] = ld4(tp + c0 + 4);                            \
        pl[slot] = ld4(tp + cL);                                \
        pr[slot] = ld4(tp + cR); }

    ISSUE(0, 0)
    ISSUE(1, 1)

    // ---- unpack input rows, per-lane input sum ----
    float iv[4][8];
    float isum = 0.f;
#pragma unroll
    for (int yi = 0; yi < 4; ++yi) {
        iv[yi][0] = ia[yi].x; iv[yi][1] = ia[yi].y;
        iv[yi][2] = ia[yi].z; iv[yi][3] = ia[yi].w;
        iv[yi][4] = ic[yi].x; iv[yi][5] = ic[yi].y;
        iv[yi][6] = ic[yi].z; iv[yi][7] = ic[yi].w;
#pragma unroll
        for (int j = 0; j < 8; ++j) isum += iv[yi][j];
    }

    float acc[25];
#pragma unroll
    for (int k = 0; k < 25; ++k) acc[k] = 0.f;
    float tsum = 0.f;

    // ---- 8 target rows (y0-2 .. y0+5); prefetch t+2 before consuming t ----
#pragma unroll
    for (int t = 0; t < 8; ++t) {
        if (t + 2 < 8) { ISSUE((t + 2) % 3, t + 2) }

        const int s = t % 3;               // compile-time under full unroll
        float tw[12];                      // tw[c] = target col c0 + c - 2
        tw[0]  = pl[s].z; tw[1]  = pl[s].w;
        tw[2]  = pa[s].x; tw[3]  = pa[s].y; tw[4] = pa[s].z; tw[5] = pa[s].w;
        tw[6]  = pc[s].x; tw[7]  = pc[s].y; tw[8] = pc[s].z; tw[9] = pc[s].w;
        tw[10] = pr[s].x; tw[11] = pr[s].y;

        if (t >= 2 && t <= 5) {            // rows y0..y0+3: count each tg elem once
#pragma unroll
            for (int j = 0; j < 8; ++j) tsum += tw[j + 2];
        }

#pragma unroll
        for (int yi = 0; yi < 4; ++yi) {
            const int sy = yi + 2 - t;     // roll shift pairing in-row yi with this tg row
            if (sy < -2 || sy > 2) continue;   // compile-time prune (20 live pairs)
#pragma unroll
            for (int sx = -2; sx <= 2; ++sx) {
#pragma unroll
                for (int j = 0; j < 8; ++j)
                    acc[(sy + 2) * 5 + (sx + 2)] += iv[yi][j] * tw[j + 2 - sx];
            }
        }
    }
#undef ISSUE
#undef TROW

    // ---- per-wave DPP reduction of 27 quantities, then per-block combine ----
#pragma unroll
    for (int k = 0; k < 25; ++k) {
        const float v = wave_sum_dpp(acc[k]);
        if (lane == 63) warr[wave][k] = v;
    }
    {
        const float v = wave_sum_dpp(isum);
        if (lane == 63) warr[wave][25] = v;
        const float u = wave_sum_dpp(tsum);
        if (lane == 63) warr[wave][26] = u;
    }

    __syncthreads();
    if (tid < 27) {
        const float s = warr[0][tid] + warr[1][tid] + warr[2][tid] + warr[3][tid];
        ws[tid * nblocks + bid] = s;   // [k][block] layout for coalesced pass 2
    }
}

// Kernel 2: 27 blocks, block k tree-reduces the per-block partials for quantity k.
__global__ __launch_bounds__(256)
void dice_reduce(const float* __restrict__ ws, float* __restrict__ tot, int nblocks) {
    __shared__ float red[4];
    const int k = blockIdx.x;
    const int tid = threadIdx.x;
    const float* p = ws + (size_t)k * nblocks;

    float s = 0.f;
    for (int i = tid; i < nblocks; i += 256) s += p[i];
    s = wave_sum_dpp(s);
    if ((tid & 63) == 63) red[tid >> 6] = s;
    __syncthreads();
    if (tid == 0) tot[k] = red[0] + red[1] + red[2] + red[3];
}

// Kernel 3: one wave — 25-way max + final loss scalar.
__global__ void dice_out(const float* __restrict__ tot, float* __restrict__ out) {
    const int tid = threadIdx.x;   // blockDim = 64
    float v = (tid < 25) ? tot[tid] : -1e30f;
#pragma unroll
    for (int off = 32; off; off >>= 1) v = fmaxf(v, __shfl_down(v, off, 64));
    if (tid == 0) {
        const float denom = tot[25] + tot[26] + 1.0f;   // i_sum + t_sum + SMOOTH
        out[0] = 1.0f - (2.0f * v + 1.0f) / denom;      // min loss == max intersection
    }
}

extern "C" void kernel_launch(void* const* d_in, const int* in_sizes, int n_in,
                              void* d_out, int out_size, void* d_ws, size_t ws_size,
                              hipStream_t stream) {
    const float* inputs  = (const float*)d_in[0];
    const float* targets = (const float*)d_in[1];
    float* out = (float*)d_out;
    float* ws  = (float*)d_ws;

    const int B = in_sizes[0] / (H * W);    // 64
    const int nblocks = B * (H / 4) / 4;    // 2048 blocks x 4 waves x 4 rows

    float* tot = ws + (size_t)27 * nblocks; // 27 scalar totals after the partial table

    dice_partial<<<nblocks, 256, 0, stream>>>(inputs, targets, ws, nblocks);
    dice_reduce<<<27, 256, 0, stream>>>(ws, tot, nblocks);
    dice_out<<<1, 64, 0, stream>>>(tot, out);
}